// Round 10
// baseline (645.497 us; speedup 1.0000x reference)
//
#include <hip/hip_runtime.h>
#include <hip/hip_fp16.h>
#include <math.h>
#include <string.h>

// GAT 2-layer, N=100000, E=1600000, F_IN=128, HID=128 (H=4,C=32), OUT=64 (H=1,C=64)
// R16 -> R17: fuse the layer-2 linear (gemm2) into agg1's epilogue.
// gemm2 row r depends only on hmid[r], which agg1 holds in registers ->
// stage 16 node rows in LDS (hm[16][128] f32, 8KB), one barrier, then each
// wave does its 4 nodes' 64-wide gemv: lane o owns output o; hm reads are
// same-address broadcasts; W2 pre-packed chunk-major (W2g[cc][o][8]) so each
// load is a coalesced 1KB wave-read of a 16KB L2-hot table. as2/ad2 via
// 64-lane shfl reductions. Eliminates the gemm2 dispatch AND the 51MB hmid
// write+read roundtrip. h2 gets its own buffer (h1 still gathered during
// agg1 -- no alias). agg1 VALUBusy was 38% -> gemv mostly hides under gather
// stalls. R16's global-interleaved rank order kept unchanged (agg 82.7us,
// occ 77%, verified).

#define BSH 9      // log2 dsts per bucket
#define DPB 512    // dsts per bucket
#define NBK 256    // max buckets (covers N < 131072)
#define CH1 16384  // edges per block in bucket_scatter
#define DBINS 512  // degree bins for per-bucket ranking (deg clamped)
#define HB 128     // histogram blocks in fused bucket_hist
#define LOG2E 1.44269504088896f

using half8 = __attribute__((ext_vector_type(8))) _Float16;
using half4 = __attribute__((ext_vector_type(4))) _Float16;
using floatx4 = __attribute__((ext_vector_type(4))) float;

__device__ __forceinline__ float exp2_fast(float x) {
#if __has_builtin(__builtin_amdgcn_exp2f)
    return __builtin_amdgcn_exp2f(x);
#else
    return exp2f(x);
#endif
}

// Write one half8 B-fragment: fid -> (k0s, t, quad, col); element j is
// W[k0s*32+quad*8+j][t*16+col]. gemm reads WtF as half8[fid] with fid =
// (k0s*NT+t)*64 + lane.
__device__ __forceinline__ void wfrag(const float* __restrict__ W, __half* __restrict__ WtF,
                                      int NC, int fid) {
    int col = fid & 15, quad = (fid >> 4) & 3, rest = fid >> 6;
    int NT = NC >> 4;
    int t = rest & (NT - 1), k0s = rest / NT;
    int n = t * 16 + col;
    int k = k0s * 32 + quad * 8;
#pragma unroll
    for (int j = 0; j < 8; ++j)
        WtF[fid * 8 + j] = __float2half(W[(k + j) * NC + n]);
}

// W2 chunk-major pack for the fused gemv: W2g[(cc*64+o)*8+j] = W2[(cc*8+j)*64+o]
// (cc = channel chunk 0..15, o = output 0..63). Wave load at lane=o is 1KB
// contiguous per chunk.
__device__ __forceinline__ void wfrag2(const float* __restrict__ W2, __half* __restrict__ W2g,
                                       int fid) {
    int o = fid & 63, cc = fid >> 6;   // fid in [0,1024)
#pragma unroll
    for (int j = 0; j < 8; ++j)
        W2g[fid * 8 + j] = __float2half(W2[(cc * 8 + j) * 64 + o]);
}

// ---------------- CSR build: bucketed counting sort ----------------
// blocks [0,HB): dst histogram; blocks [HB,...): weight prep (independent work).

__global__ __launch_bounds__(256) void bucket_hist(const int* __restrict__ ei, int E, int N,
                                                   unsigned* __restrict__ bcount,
                                                   const float* __restrict__ W1,
                                                   const float* __restrict__ W2,
                                                   __half* __restrict__ WtF1,
                                                   __half* __restrict__ W2g) {
    if (blockIdx.x >= HB) {
        int tid = (blockIdx.x - HB) * 256 + threadIdx.x;
        if (tid < 2048) wfrag(W1, WtF1, 128, tid);            // 4*8*64 frags
        else if (tid < 3072) wfrag2(W2, W2g, tid - 2048);     // 16*64 chunks
        return;
    }
    __shared__ unsigned hist[NBK];
    int t = threadIdx.x;
    hist[t] = 0;
    __syncthreads();
    int Etot = E + N;
    for (int k = blockIdx.x * 256 + t; k < Etot; k += HB * 256) {
        int d = (k < E) ? ei[E + k] : (k - E);
        atomicAdd(&hist[d >> BSH], 1u);
    }
    __syncthreads();
    unsigned c = hist[t];
    if (c) atomicAdd(&bcount[t], c);
}

__global__ void scan_buckets(const unsigned* __restrict__ bcount, unsigned* __restrict__ bbase,
                             unsigned* __restrict__ bcursor) {
    __shared__ unsigned s[NBK];
    int t = threadIdx.x;
    unsigned v = bcount[t];
    s[t] = v;
    __syncthreads();
    for (int o = 1; o < NBK; o <<= 1) {
        unsigned add = (t >= o) ? s[t - o] : 0;
        __syncthreads();
        s[t] += add;
        __syncthreads();
    }
    unsigned excl = s[t] - v;
    bbase[t] = excl;
    bcursor[t] = excl;
    if (t == NBK - 1) bbase[NBK] = excl + v;   // = Etot
}

// rec word: src in bits [0,17), dst low 9 bits in [17,26)
__global__ __launch_bounds__(256) void bucket_scatter(const int* __restrict__ ei, int E, int N,
                                                      unsigned* __restrict__ bcursor,
                                                      unsigned* __restrict__ rec) {
    __shared__ unsigned hist[NBK];
    __shared__ unsigned base[NBK];
    int t = threadIdx.x;
    hist[t] = 0;
    __syncthreads();
    int Etot = E + N;
    int k0 = blockIdx.x * CH1;
    int k1 = min(k0 + CH1, Etot);
    for (int k = k0 + t; k < k1; k += 256) {
        int d = (k < E) ? ei[E + k] : (k - E);
        atomicAdd(&hist[d >> BSH], 1u);
    }
    __syncthreads();
    unsigned c = hist[t];
    base[t] = c ? atomicAdd(&bcursor[t], c) : 0u;
    hist[t] = 0;
    __syncthreads();
    for (int k = k0 + t; k < k1; k += 256) {
        int s, d;
        if (k < E) { s = ei[k]; d = ei[E + k]; } else { s = d = k - E; }
        int b = d >> BSH;
        unsigned r = atomicAdd(&hist[b], 1u);
        rec[base[b] + r] = (unsigned)s | ((unsigned)(d & (DPB - 1)) << 17);
    }
}

// ---------------- bucket_sort + fused global-interleaved degree rank ----------------

__global__ __launch_bounds__(256) void bucket_sort(const unsigned* __restrict__ rec,
                                                   const unsigned* __restrict__ bbase,
                                                   int* __restrict__ offs, int* __restrict__ srcs,
                                                   int* __restrict__ order,
                                                   int N, int Etot) {
    __shared__ unsigned hist[DPB];
    __shared__ unsigned tsum[256];
    __shared__ unsigned deg_l[DBINS];   // per-bucket degree-rank histogram
    int t = threadIdx.x, bb = blockIdx.x;
    unsigned r0 = bbase[bb], r1 = bbase[bb + 1];
    hist[t] = 0;
    hist[t + 256] = 0;
    deg_l[t] = 0;
    deg_l[t + 256] = 0;
    __syncthreads();
    int dlo = bb << BSH;
    for (unsigned k = r0 + t; k < r1; k += 256) {
        unsigned e = rec[k];
        atomicAdd(&hist[e >> 17], 1u);
    }
    __syncthreads();
    unsigned h0 = hist[2 * t], h1 = hist[2 * t + 1];
    int d0 = dlo + 2 * t;
    // descending-degree bins (bin 0 = heaviest) + per-bin sub-rank
    unsigned b0 = DBINS - 1u - min(h0, (unsigned)(DBINS - 1));
    unsigned b1 = DBINS - 1u - min(h1, (unsigned)(DBINS - 1));
    unsigned sub0 = 0, sub1 = 0;
    if (d0 < N) sub0 = atomicAdd(&deg_l[b0], 1u);
    if (d0 + 1 < N) sub1 = atomicAdd(&deg_l[b1], 1u);
    tsum[t] = h0 + h1;
    __syncthreads();
    for (int o = 1; o < 256; o <<= 1) {
        unsigned a = (t >= o) ? tsum[t - o] : 0;
        __syncthreads();
        tsum[t] += a;
        __syncthreads();
    }
    unsigned tb = tsum[t] - (h0 + h1);
    if (d0 < N) offs[d0] = (int)(r0 + tb);
    if (d0 + 1 < N) offs[d0 + 1] = (int)(r0 + tb + h0);
    hist[2 * t] = tb;            // reuse as relative cursors
    hist[2 * t + 1] = tb + h0;
    __syncthreads();
    for (unsigned k = r0 + t; k < r1; k += 256) {
        unsigned e = rec[k];
        unsigned r = atomicAdd(&hist[e >> 17], 1u);
        srcs[r0 + r] = (int)(e & 0x1FFFFu);
    }
    if (bb == 0 && t == 0) offs[N] = Etot;
    __syncthreads();             // hist cursor role done; reuse as count copy
    // exclusive scan of deg_l (512 bins, 2/thread Hillis-Steele).
    // rank = excl[bin] + sub (0 = heaviest in bucket).
    unsigned c0 = deg_l[t], c1 = deg_l[t + 256];
    hist[t] = c0;
    hist[t + 256] = c1;
    __syncthreads();
    for (int o = 1; o < DBINS; o <<= 1) {
        unsigned a0 = (t >= o) ? deg_l[t - o] : 0u;
        unsigned a1 = (t + 256 >= o) ? deg_l[t + 256 - o] : 0u;
        __syncthreads();
        deg_l[t] += a0;
        deg_l[t + 256] += a1;
        __syncthreads();
    }
    // Global-interleaved slot: rank class r holds one node per bucket that has
    // >= r+1 nodes. NFULL full buckets + tail of TAIL nodes (bucket NFULL).
    // base(r) = r*NFULL + min(r,TAIL); slot = base(r) + bb. Exact bijection.
    int NFULL = N >> BSH;
    unsigned TAIL = (unsigned)(N - (NFULL << BSH));
    if (d0 < N) {
        unsigned r = deg_l[b0] - hist[b0] + sub0;
        order[(int)(r * (unsigned)NFULL + min(r, TAIL)) + bb] = d0;
    }
    if (d0 + 1 < N) {
        unsigned r = deg_l[b1] - hist[b1] + sub1;
        order[(int)(r * (unsigned)NFULL + min(r, TAIL)) + bb] = d0 + 1;
    }
}

// ---------------- MFMA GEMM + fused alphas (layer 1) ----------------
// C[M,NC] = A[M,128] * W[128,NC]; W in fragment-major fp16 layout WtF (see
// wfrag). 4 waves/block; wave computes 16 rows x NC cols, no LDS; B loads are
// wf[lane] -> fully coalesced 1KB per (k0s,t).
// Epilogue: fp16 C store + as/ad = (C . a_src/a_dst) per head, 16-lane shfl.

template <int NC, int H, typename InT>
__global__ __launch_bounds__(256) void gemm_mfma(const InT* __restrict__ A,
                                                 const __half* __restrict__ WtF,
                                                 __half* __restrict__ C,
                                                 const float* __restrict__ a_src,
                                                 const float* __restrict__ a_dst,
                                                 float* __restrict__ as,
                                                 float* __restrict__ ad, int M) {
    constexpr int NT = NC / 16;      // col tiles (8 or 4)
    constexpr int TPH = NT / H;      // tiles per head (2 or 4)
    int wave = threadIdx.x >> 6;
    int lane = threadIdx.x & 63;
    int quad = lane >> 4, col = lane & 15;
    int row0 = blockIdx.x * 64 + wave * 16;
    int arow = row0 + col;           // A fragment row (m = lane&15)
    if (arow >= M) arow = M - 1;
    floatx4 acc[NT] = {};
    const half8* wf = reinterpret_cast<const half8*>(WtF) + lane;
#pragma unroll
    for (int k0s = 0; k0s < 4; ++k0s) {
        int k0 = k0s * 32;
        half8 af;
        if constexpr (sizeof(InT) == 4) {
            const float* ap = (const float*)A + (size_t)arow * 128 + k0 + quad * 8;
            float4 v0 = *reinterpret_cast<const float4*>(ap);
            float4 v1 = *reinterpret_cast<const float4*>(ap + 4);
            af[0] = (_Float16)v0.x; af[1] = (_Float16)v0.y;
            af[2] = (_Float16)v0.z; af[3] = (_Float16)v0.w;
            af[4] = (_Float16)v1.x; af[5] = (_Float16)v1.y;
            af[6] = (_Float16)v1.z; af[7] = (_Float16)v1.w;
        } else {
            af = *reinterpret_cast<const half8*>((const __half*)A + (size_t)arow * 128 + k0 + quad * 8);
        }
#pragma unroll
        for (int t = 0; t < NT; ++t) {
            half8 bf = wf[(k0s * NT + t) * 64];
            acc[t] = __builtin_amdgcn_mfma_f32_16x16x32_f16(af, bf, acc[t], 0, 0, 0);
        }
    }
    // epilogue
    float sa[NT], da[NT];
#pragma unroll
    for (int t = 0; t < NT; ++t) {
        sa[t] = a_src[t * 16 + col];
        da[t] = a_dst[t * 16 + col];
    }
    int rbase = row0 + quad * 4;
#pragma unroll
    for (int reg = 0; reg < 4; ++reg) {
        int row = rbase + reg;
        bool live = row < M;
        if (live) {
#pragma unroll
            for (int t = 0; t < NT; ++t)
                C[(size_t)row * NC + t * 16 + col] = __float2half(acc[t][reg]);
        }
#pragma unroll
        for (int h = 0; h < H; ++h) {
            float ps = 0.f, pd = 0.f;
#pragma unroll
            for (int tt = 0; tt < TPH; ++tt) {
                int t = h * TPH + tt;
                ps = fmaf(acc[t][reg], sa[t], ps);
                pd = fmaf(acc[t][reg], da[t], pd);
            }
#pragma unroll
            for (int o = 1; o < 16; o <<= 1) {
                ps += __shfl_xor(ps, o, 64);
                pd += __shfl_xor(pd, o, 64);
            }
            if (col == 0 && live) {
                as[(size_t)row * H + h] = ps * LOG2E;
                ad[(size_t)row * H + h] = pd * LOG2E;
            }
        }
    }
}

// ---------------- layer-1 aggregation + fused layer-2 linear ----------------
// Gather phase identical to aggregateQ<4,128,128,true>. Then: stage the 16
// post-ELU node rows in LDS, one barrier, and each wave computes its 4 nodes'
// h2 = hm . W2 (lane o = output o), as2/ad2 via 64-lane reductions.

__global__ __launch_bounds__(256) void aggregate1F(const __half* __restrict__ h,
                                                   const float* __restrict__ as,
                                                   const float* __restrict__ ad,
                                                   const int* __restrict__ offs,
                                                   const int* __restrict__ srcs,
                                                   const int* __restrict__ order,
                                                   const float* __restrict__ bias,
                                                   const __half* __restrict__ W2g,
                                                   const float* __restrict__ a_src2,
                                                   const float* __restrict__ a_dst2,
                                                   __half* __restrict__ h2,
                                                   float* __restrict__ as2,
                                                   float* __restrict__ ad2, int N) {
    constexpr int CPL = 8, H = 4, ROWS = 128;
    __shared__ float hm[16][128];
    unsigned wave = (blockIdx.x * blockDim.x + threadIdx.x) >> 6;
    unsigned lane = threadIdx.x & 63;
    unsigned lig = lane & 15;       // lane in group
    unsigned g = lane >> 4;         // group (node) within wave
    unsigned idx = wave * 4u + g;
    bool live = idx < (unsigned)N;
    unsigned nc = (unsigned)order[live ? idx : 0u];
    unsigned chan = lig * CPL;
    unsigned head = (chan * H) / ROWS;
    float adv = ad[nc * H + head];
    int e0 = offs[nc], e1 = offs[nc + 1];
    int deg = e1 - e0, e1m1 = e1 - 1;
    int md = deg;
    md = max(md, __shfl_xor(md, 16, 64));
    md = max(md, __shfl_xor(md, 32, 64));
    float accs[CPL] = {};
    float den = 0.f;
    for (int k = 0; k < md; k += 4) {
        int b = e0 + k;
        unsigned j0 = (unsigned)srcs[min(b, e1m1)];
        unsigned j1 = (unsigned)srcs[min(b + 1, e1m1)];
        unsigned j2 = (unsigned)srcs[min(b + 2, e1m1)];
        unsigned j3 = (unsigned)srcs[min(b + 3, e1m1)];
        float t0 = as[j0 * H + head] + adv;
        float t1 = as[j1 * H + head] + adv;
        float t2 = as[j2 * H + head] + adv;
        float t3 = as[j3 * H + head] + adv;
        _Float16 f0[CPL], f1[CPL], f2[CPL], f3[CPL];
        {
            half8 v0 = *reinterpret_cast<const half8*>(h + j0 * (unsigned)ROWS + chan);
            half8 v1 = *reinterpret_cast<const half8*>(h + j1 * (unsigned)ROWS + chan);
            half8 v2 = *reinterpret_cast<const half8*>(h + j2 * (unsigned)ROWS + chan);
            half8 v3 = *reinterpret_cast<const half8*>(h + j3 * (unsigned)ROWS + chan);
#pragma unroll
            for (int c = 0; c < CPL; ++c) { f0[c] = v0[c]; f1[c] = v1[c]; f2[c] = v2[c]; f3[c] = v3[c]; }
        }
        float x0 = exp2_fast(fmaxf(t0, 0.2f * t0));
        float x1 = exp2_fast(fmaxf(t1, 0.2f * t1));
        float x2 = exp2_fast(fmaxf(t2, 0.2f * t2));
        float x3 = exp2_fast(fmaxf(t3, 0.2f * t3));
        x0 = (k < deg) ? x0 : 0.f;
        x1 = (k + 1 < deg) ? x1 : 0.f;
        x2 = (k + 2 < deg) ? x2 : 0.f;
        x3 = (k + 3 < deg) ? x3 : 0.f;
#pragma unroll
        for (int c = 0; c < CPL; ++c) accs[c] = fmaf(x0, (float)f0[c], accs[c]);
#pragma unroll
        for (int c = 0; c < CPL; ++c) accs[c] = fmaf(x1, (float)f1[c], accs[c]);
#pragma unroll
        for (int c = 0; c < CPL; ++c) accs[c] = fmaf(x2, (float)f2[c], accs[c]);
#pragma unroll
        for (int c = 0; c < CPL; ++c) accs[c] = fmaf(x3, (float)f3[c], accs[c]);
        den += x0 + x1;
        den += x2 + x3;
    }
    float r = 1.0f / (den + 1e-16f);
    // post-ELU row -> LDS (garbage for dead nodes; never stored)
    unsigned w_in_b = threadIdx.x >> 6;
    unsigned nib = w_in_b * 4 + g;
    const float* bp = bias + chan;
#pragma unroll
    for (int c = 0; c < CPL; ++c) {
        float v = accs[c] * r + bp[c];
        v = (v > 0.f) ? v : expm1f(v);
        hm[nib][chan + c] = v;
    }
    __syncthreads();
    // fused layer-2 gemv: lane o computes output o for the wave's 4 nodes
    int o = (int)lane;
    float ag[4] = {0.f, 0.f, 0.f, 0.f};
    const half8* wg = reinterpret_cast<const half8*>(W2g);
    int wb = (int)w_in_b * 4;
#pragma unroll
    for (int cc = 0; cc < 16; ++cc) {
        half8 w = wg[cc * 64 + o];
        float wf[8];
#pragma unroll
        for (int j = 0; j < 8; ++j) wf[j] = (float)w[j];
#pragma unroll
        for (int gg = 0; gg < 4; ++gg) {
            const floatx4* hp = reinterpret_cast<const floatx4*>(&hm[wb + gg][cc * 8]);
            floatx4 a = hp[0], b2v = hp[1];
            ag[gg] = fmaf(a[0], wf[0], ag[gg]);
            ag[gg] = fmaf(a[1], wf[1], ag[gg]);
            ag[gg] = fmaf(a[2], wf[2], ag[gg]);
            ag[gg] = fmaf(a[3], wf[3], ag[gg]);
            ag[gg] = fmaf(b2v[0], wf[4], ag[gg]);
            ag[gg] = fmaf(b2v[1], wf[5], ag[gg]);
            ag[gg] = fmaf(b2v[2], wf[6], ag[gg]);
            ag[gg] = fmaf(b2v[3], wf[7], ag[gg]);
        }
    }
    float s2 = a_src2[o], d2 = a_dst2[o];
#pragma unroll
    for (int gg = 0; gg < 4; ++gg) {
        float hv = ag[gg];
        float ps = hv * s2, pd = hv * d2;
#pragma unroll
        for (int off = 1; off < 64; off <<= 1) {
            ps += __shfl_xor(ps, off, 64);
            pd += __shfl_xor(pd, off, 64);
        }
        bool glive = (wave * 4u + (unsigned)gg) < (unsigned)N;
        unsigned ng = (unsigned)__shfl((int)nc, gg * 16, 64);
        if (glive) {
            h2[ng * 64u + (unsigned)o] = __float2half(hv);
            if (lane == 0) { as2[ng] = ps * LOG2E; ad2[ng] = pd * LOG2E; }
        }
    }
}

// ---------------- aggregation (layer 2): 4 dst nodes per wave ----------------

template <int CPL>
__device__ __forceinline__ void ldrow(const __half* __restrict__ p, _Float16* f) {
    if constexpr (CPL == 8) {
        half8 v = *reinterpret_cast<const half8*>(p);
#pragma unroll
        for (int c = 0; c < 8; ++c) f[c] = v[c];
    } else {
        half4 v = *reinterpret_cast<const half4*>(p);
#pragma unroll
        for (int c = 0; c < 4; ++c) f[c] = v[c];
    }
}

template <int H, int ROWS, int CW, bool DOELU, typename OutT>
__global__ __launch_bounds__(256) void aggregateQ(const __half* __restrict__ h,
                                                  const float* __restrict__ as,
                                                  const float* __restrict__ ad,
                                                  const int* __restrict__ offs,
                                                  const int* __restrict__ srcs,
                                                  const int* __restrict__ order,
                                                  const float* __restrict__ bias,
                                                  OutT* __restrict__ out, int N) {
    constexpr int CPL = CW / 16;    // channels per lane (8 or 4)
    unsigned wave = (blockIdx.x * blockDim.x + threadIdx.x) >> 6;
    unsigned lane = threadIdx.x & 63;
    unsigned lig = lane & 15;       // lane in group
    unsigned idx = wave * 4u + (lane >> 4);
    bool live = idx < (unsigned)N;
    unsigned nc = (unsigned)order[live ? idx : 0u];
    unsigned chan = lig * CPL;
    unsigned head = (chan * H) / ROWS;
    float adv = ad[nc * H + head];
    int e0 = offs[nc], e1 = offs[nc + 1];
    int deg = e1 - e0, e1m1 = e1 - 1;
    int md = deg;
    md = max(md, __shfl_xor(md, 16, 64));
    md = max(md, __shfl_xor(md, 32, 64));
    float accs[CPL] = {};
    float den = 0.f;
    for (int k = 0; k < md; k += 4) {
        int b = e0 + k;
        unsigned j0 = (unsigned)srcs[min(b, e1m1)];
        unsigned j1 = (unsigned)srcs[min(b + 1, e1m1)];
        unsigned j2 = (unsigned)srcs[min(b + 2, e1m1)];
        unsigned j3 = (unsigned)srcs[min(b + 3, e1m1)];
        float t0 = as[j0 * H + head] + adv;
        float t1 = as[j1 * H + head] + adv;
        float t2 = as[j2 * H + head] + adv;
        float t3 = as[j3 * H + head] + adv;
        _Float16 f0[CPL], f1[CPL], f2[CPL], f3[CPL];
        ldrow<CPL>(h + j0 * (unsigned)ROWS + chan, f0);
        ldrow<CPL>(h + j1 * (unsigned)ROWS + chan, f1);
        ldrow<CPL>(h + j2 * (unsigned)ROWS + chan, f2);
        ldrow<CPL>(h + j3 * (unsigned)ROWS + chan, f3);
        float x0 = exp2_fast(fmaxf(t0, 0.2f * t0));
        float x1 = exp2_fast(fmaxf(t1, 0.2f * t1));
        float x2 = exp2_fast(fmaxf(t2, 0.2f * t2));
        float x3 = exp2_fast(fmaxf(t3, 0.2f * t3));
        x0 = (k < deg) ? x0 : 0.f;
        x1 = (k + 1 < deg) ? x1 : 0.f;
        x2 = (k + 2 < deg) ? x2 : 0.f;
        x3 = (k + 3 < deg) ? x3 : 0.f;
#pragma unroll
        for (int c = 0; c < CPL; ++c) accs[c] = fmaf(x0, (float)f0[c], accs[c]);
#pragma unroll
        for (int c = 0; c < CPL; ++c) accs[c] = fmaf(x1, (float)f1[c], accs[c]);
#pragma unroll
        for (int c = 0; c < CPL; ++c) accs[c] = fmaf(x2, (float)f2[c], accs[c]);
#pragma unroll
        for (int c = 0; c < CPL; ++c) accs[c] = fmaf(x3, (float)f3[c], accs[c]);
        den += x0 + x1;
        den += x2 + x3;
    }
    float r = 1.0f / (den + 1e-16f);
    if (!live) return;
    const float* bp = bias + chan;
    float vs[CPL];
#pragma unroll
    for (int c = 0; c < CPL; ++c) {
        float v = accs[c] * r + bp[c];
        if constexpr (DOELU) v = (v > 0.f) ? v : expm1f(v);
        vs[c] = v;
    }
    if constexpr (sizeof(OutT) == 2) {
        __half2 st[CPL / 2];
#pragma unroll
        for (int q = 0; q < CPL / 2; ++q)
            st[q] = __floats2half2_rn(vs[2 * q], vs[2 * q + 1]);
        if constexpr (CPL == 8) {
            uint4 v; memcpy(&v, st, 16);
            *reinterpret_cast<uint4*>((__half*)out + nc * (unsigned)ROWS + chan) = v;
        } else {
            uint2 v; memcpy(&v, st, 8);
            *reinterpret_cast<uint2*>((__half*)out + nc * (unsigned)ROWS + chan) = v;
        }
    } else {
#pragma unroll
        for (int q4 = 0; q4 < CPL; q4 += 4) {
            float4 v = make_float4(vs[q4], vs[q4 + 1], vs[q4 + 2], vs[q4 + 3]);
            *reinterpret_cast<float4*>((float*)out + nc * (unsigned)ROWS + chan + q4) = v;
        }
    }
}

// ---------------- launch ----------------

extern "C" void kernel_launch(void* const* d_in, const int* in_sizes, int n_in,
                              void* d_out, int out_size, void* d_ws, size_t ws_size,
                              hipStream_t stream) {
    const float* x      = (const float*)d_in[0];
    const int*   ei     = (const int*)d_in[1];
    const float* W1     = (const float*)d_in[2];
    const float* a_src1 = (const float*)d_in[3];
    const float* a_dst1 = (const float*)d_in[4];
    const float* b1     = (const float*)d_in[5];
    const float* W2     = (const float*)d_in[6];
    const float* a_src2 = (const float*)d_in[7];
    const float* a_dst2 = (const float*)d_in[8];
    const float* b2     = (const float*)d_in[9];
    float* out = (float*)d_out;

    const int N = out_size / 64;          // 100000
    const int E = in_sizes[1] / 2;        // 1600000
    const int Etot = E + N;

    size_t off = 0;
    auto carve = [&](size_t bytes) -> void* {
        void* p = (char*)d_ws + off;
        off += (bytes + 255) & ~(size_t)255;
        return p;
    };
    __half* h1      = (__half*)carve((size_t)N * 128 * 2);   // fp16 h, layer 1
    __half* h2      = (__half*)carve((size_t)N * 64 * 2);    // fp16 h, layer 2 (own buffer!)
    float* as1      = (float*)carve((size_t)N * 4 * 4);
    float* ad1      = (float*)carve((size_t)N * 4 * 4);
    float* as2      = (float*)carve((size_t)N * 4);
    float* ad2      = (float*)carve((size_t)N * 4);
    int*   offs     = (int*)carve((size_t)(N + 1) * 4);
    int*   srcs     = (int*)carve((size_t)Etot * 4);
    unsigned* rec   = (unsigned*)carve((size_t)Etot * 4);
    int*   order    = (int*)carve((size_t)N * 4);            // own buffer (no rec alias)
    unsigned* bcount  = (unsigned*)carve(NBK * 4);
    unsigned* bbase   = (unsigned*)carve((NBK + 1) * 4);
    unsigned* bcursor = (unsigned*)carve(NBK * 4);
    __half* WtF1    = (__half*)carve(128 * 128 * 2);
    __half* W2g     = (__half*)carve(64 * 128 * 2);

    const int NSB = (N + DPB - 1) / DPB;   // sort blocks (196)
    const int GB  = (N + 63) / 64;         // gemm blocks (1563)

    // CSR build via bucketed counting sort (shared by both layers);
    // weight prep rides along as extra blocks (independent work).
    hipMemsetAsync(bcount, 0, NBK * sizeof(unsigned), stream);
    bucket_hist<<<HB + 12, 256, 0, stream>>>(ei, E, N, bcount, W1, W2, WtF1, W2g);
    scan_buckets<<<1, 256, 0, stream>>>(bcount, bbase, bcursor);
    bucket_scatter<<<(Etot + CH1 - 1) / CH1, 256, 0, stream>>>(ei, E, N, bcursor, rec);
    bucket_sort<<<NSB, 256, 0, stream>>>(rec, bbase, offs, srcs, order, N, Etot);

    // Layer 1: MFMA gemm (alphas fused) + aggregation with fused layer-2 linear
    gemm_mfma<128, 4, float><<<GB, 256, 0, stream>>>(
        x, WtF1, h1, a_src1, a_dst1, as1, ad1, N);
    aggregate1F<<<(N + 15) / 16, 256, 0, stream>>>(
        h1, as1, ad1, offs, srcs, order, b1, W2g, a_src2, a_dst2, h2, as2, ad2, N);

    // Layer 2 aggregation (gemm2 eliminated)
    aggregateQ<1, 64, 64, false, float><<<(N + 15) / 16, 256, 0, stream>>>(
        h2, as2, ad2, offs, srcs, order, b2, out, N);
}

// Round 11
// 350.432 us; speedup vs baseline: 1.8420x; 1.8420x over previous
//
#include <hip/hip_runtime.h>
#include <hip/hip_fp16.h>
#include <math.h>
#include <string.h>

// GAT 2-layer, N=100000, E=1600000, F_IN=128, HID=128 (H=4,C=32), OUT=64 (H=1,C=64)
// R17 -> R18: REVERT to R16 (350.7us verified best). R17's gemv-into-agg1
// fusion: VGPR 32->256, occupancy 77->2-11%, 137MB spill traffic, 398us.
// Third confirmation of the session rule: the gather kernel lives on 32-VGPR
// max-occupancy TLP; never graft compute state into it (R11 fusion, R13 nt,
// R17 gemv). The 51MB hmid roundtrip via a separate register-lean MFMA
// dispatch is the cheaper structure. R16 state: fragment-major W (coalesced
// B-frags), global-interleaved degree-rank order fused into bucket_sort
// (agg occ 77%, zero ordering dispatches), 4-edge unrolled gather.

#define BSH 9      // log2 dsts per bucket
#define DPB 512    // dsts per bucket
#define NBK 256    // max buckets (covers N < 131072)
#define CH1 16384  // edges per block in bucket_scatter
#define DBINS 512  // degree bins for per-bucket ranking (deg clamped)
#define HB 128     // histogram blocks in fused bucket_hist
#define LOG2E 1.44269504088896f

using half8 = __attribute__((ext_vector_type(8))) _Float16;
using half4 = __attribute__((ext_vector_type(4))) _Float16;
using floatx4 = __attribute__((ext_vector_type(4))) float;

__device__ __forceinline__ float exp2_fast(float x) {
#if __has_builtin(__builtin_amdgcn_exp2f)
    return __builtin_amdgcn_exp2f(x);
#else
    return exp2f(x);
#endif
}

// Write one half8 B-fragment: fid -> (k0s, t, quad, col); element j is
// W[k0s*32+quad*8+j][t*16+col]. gemm reads WtF as half8[fid] with fid =
// (k0s*NT+t)*64 + lane.
__device__ __forceinline__ void wfrag(const float* __restrict__ W, __half* __restrict__ WtF,
                                      int NC, int fid) {
    int col = fid & 15, quad = (fid >> 4) & 3, rest = fid >> 6;
    int NT = NC >> 4;
    int t = rest & (NT - 1), k0s = rest / NT;
    int n = t * 16 + col;
    int k = k0s * 32 + quad * 8;
#pragma unroll
    for (int j = 0; j < 8; ++j)
        WtF[fid * 8 + j] = __float2half(W[(k + j) * NC + n]);
}

// ---------------- CSR build: bucketed counting sort ----------------
// blocks [0,HB): dst histogram; blocks [HB,...): weight fragment prep (independent work).

__global__ __launch_bounds__(256) void bucket_hist(const int* __restrict__ ei, int E, int N,
                                                   unsigned* __restrict__ bcount,
                                                   const float* __restrict__ W1,
                                                   const float* __restrict__ W2,
                                                   __half* __restrict__ WtF1,
                                                   __half* __restrict__ WtF2) {
    if (blockIdx.x >= HB) {
        int tid = (blockIdx.x - HB) * 256 + threadIdx.x;
        if (tid < 2048) wfrag(W1, WtF1, 128, tid);          // 4*8*64 frags
        else if (tid < 3072) wfrag(W2, WtF2, 64, tid - 2048); // 4*4*64 frags
        return;
    }
    __shared__ unsigned hist[NBK];
    int t = threadIdx.x;
    hist[t] = 0;
    __syncthreads();
    int Etot = E + N;
    for (int k = blockIdx.x * 256 + t; k < Etot; k += HB * 256) {
        int d = (k < E) ? ei[E + k] : (k - E);
        atomicAdd(&hist[d >> BSH], 1u);
    }
    __syncthreads();
    unsigned c = hist[t];
    if (c) atomicAdd(&bcount[t], c);
}

__global__ void scan_buckets(const unsigned* __restrict__ bcount, unsigned* __restrict__ bbase,
                             unsigned* __restrict__ bcursor) {
    __shared__ unsigned s[NBK];
    int t = threadIdx.x;
    unsigned v = bcount[t];
    s[t] = v;
    __syncthreads();
    for (int o = 1; o < NBK; o <<= 1) {
        unsigned add = (t >= o) ? s[t - o] : 0;
        __syncthreads();
        s[t] += add;
        __syncthreads();
    }
    unsigned excl = s[t] - v;
    bbase[t] = excl;
    bcursor[t] = excl;
    if (t == NBK - 1) bbase[NBK] = excl + v;   // = Etot
}

// rec word: src in bits [0,17), dst low 9 bits in [17,26)
__global__ __launch_bounds__(256) void bucket_scatter(const int* __restrict__ ei, int E, int N,
                                                      unsigned* __restrict__ bcursor,
                                                      unsigned* __restrict__ rec) {
    __shared__ unsigned hist[NBK];
    __shared__ unsigned base[NBK];
    int t = threadIdx.x;
    hist[t] = 0;
    __syncthreads();
    int Etot = E + N;
    int k0 = blockIdx.x * CH1;
    int k1 = min(k0 + CH1, Etot);
    for (int k = k0 + t; k < k1; k += 256) {
        int d = (k < E) ? ei[E + k] : (k - E);
        atomicAdd(&hist[d >> BSH], 1u);
    }
    __syncthreads();
    unsigned c = hist[t];
    base[t] = c ? atomicAdd(&bcursor[t], c) : 0u;
    hist[t] = 0;
    __syncthreads();
    for (int k = k0 + t; k < k1; k += 256) {
        int s, d;
        if (k < E) { s = ei[k]; d = ei[E + k]; } else { s = d = k - E; }
        int b = d >> BSH;
        unsigned r = atomicAdd(&hist[b], 1u);
        rec[base[b] + r] = (unsigned)s | ((unsigned)(d & (DPB - 1)) << 17);
    }
}

// ---------------- bucket_sort + fused global-interleaved degree rank ----------------

__global__ __launch_bounds__(256) void bucket_sort(const unsigned* __restrict__ rec,
                                                   const unsigned* __restrict__ bbase,
                                                   int* __restrict__ offs, int* __restrict__ srcs,
                                                   int* __restrict__ order,
                                                   int N, int Etot) {
    __shared__ unsigned hist[DPB];
    __shared__ unsigned tsum[256];
    __shared__ unsigned deg_l[DBINS];   // per-bucket degree-rank histogram
    int t = threadIdx.x, bb = blockIdx.x;
    unsigned r0 = bbase[bb], r1 = bbase[bb + 1];
    hist[t] = 0;
    hist[t + 256] = 0;
    deg_l[t] = 0;
    deg_l[t + 256] = 0;
    __syncthreads();
    int dlo = bb << BSH;
    for (unsigned k = r0 + t; k < r1; k += 256) {
        unsigned e = rec[k];
        atomicAdd(&hist[e >> 17], 1u);
    }
    __syncthreads();
    unsigned h0 = hist[2 * t], h1 = hist[2 * t + 1];
    int d0 = dlo + 2 * t;
    // descending-degree bins (bin 0 = heaviest) + per-bin sub-rank
    unsigned b0 = DBINS - 1u - min(h0, (unsigned)(DBINS - 1));
    unsigned b1 = DBINS - 1u - min(h1, (unsigned)(DBINS - 1));
    unsigned sub0 = 0, sub1 = 0;
    if (d0 < N) sub0 = atomicAdd(&deg_l[b0], 1u);
    if (d0 + 1 < N) sub1 = atomicAdd(&deg_l[b1], 1u);
    tsum[t] = h0 + h1;
    __syncthreads();
    for (int o = 1; o < 256; o <<= 1) {
        unsigned a = (t >= o) ? tsum[t - o] : 0;
        __syncthreads();
        tsum[t] += a;
        __syncthreads();
    }
    unsigned tb = tsum[t] - (h0 + h1);
    if (d0 < N) offs[d0] = (int)(r0 + tb);
    if (d0 + 1 < N) offs[d0 + 1] = (int)(r0 + tb + h0);
    hist[2 * t] = tb;            // reuse as relative cursors
    hist[2 * t + 1] = tb + h0;
    __syncthreads();
    for (unsigned k = r0 + t; k < r1; k += 256) {
        unsigned e = rec[k];
        unsigned r = atomicAdd(&hist[e >> 17], 1u);
        srcs[r0 + r] = (int)(e & 0x1FFFFu);
    }
    if (bb == 0 && t == 0) offs[N] = Etot;
    __syncthreads();             // hist cursor role done; reuse as count copy
    // exclusive scan of deg_l (512 bins, 2/thread Hillis-Steele).
    // rank = excl[bin] + sub (0 = heaviest in bucket).
    unsigned c0 = deg_l[t], c1 = deg_l[t + 256];
    hist[t] = c0;
    hist[t + 256] = c1;
    __syncthreads();
    for (int o = 1; o < DBINS; o <<= 1) {
        unsigned a0 = (t >= o) ? deg_l[t - o] : 0u;
        unsigned a1 = (t + 256 >= o) ? deg_l[t + 256 - o] : 0u;
        __syncthreads();
        deg_l[t] += a0;
        deg_l[t + 256] += a1;
        __syncthreads();
    }
    // Global-interleaved slot: rank class r holds one node per bucket that has
    // >= r+1 nodes. NFULL full buckets + tail of TAIL nodes (bucket NFULL).
    // base(r) = r*NFULL + min(r,TAIL); slot = base(r) + bb. Exact bijection.
    int NFULL = N >> BSH;
    unsigned TAIL = (unsigned)(N - (NFULL << BSH));
    if (d0 < N) {
        unsigned r = deg_l[b0] - hist[b0] + sub0;
        order[(int)(r * (unsigned)NFULL + min(r, TAIL)) + bb] = d0;
    }
    if (d0 + 1 < N) {
        unsigned r = deg_l[b1] - hist[b1] + sub1;
        order[(int)(r * (unsigned)NFULL + min(r, TAIL)) + bb] = d0 + 1;
    }
}

// ---------------- MFMA GEMM + fused alphas ----------------
// C[M,NC] = A[M,128] * W[128,NC]; W in fragment-major fp16 layout WtF (see
// wfrag). 4 waves/block; wave computes 16 rows x NC cols, no LDS; B loads are
// wf[lane] -> fully coalesced 1KB per (k0s,t).
// Epilogue: fp16 C store + as/ad = (C . a_src/a_dst) per head, 16-lane shfl.

template <int NC, int H, typename InT>
__global__ __launch_bounds__(256) void gemm_mfma(const InT* __restrict__ A,
                                                 const __half* __restrict__ WtF,
                                                 __half* __restrict__ C,
                                                 const float* __restrict__ a_src,
                                                 const float* __restrict__ a_dst,
                                                 float* __restrict__ as,
                                                 float* __restrict__ ad, int M) {
    constexpr int NT = NC / 16;      // col tiles (8 or 4)
    constexpr int TPH = NT / H;      // tiles per head (2 or 4)
    int wave = threadIdx.x >> 6;
    int lane = threadIdx.x & 63;
    int quad = lane >> 4, col = lane & 15;
    int row0 = blockIdx.x * 64 + wave * 16;
    int arow = row0 + col;           // A fragment row (m = lane&15)
    if (arow >= M) arow = M - 1;
    floatx4 acc[NT] = {};
    const half8* wf = reinterpret_cast<const half8*>(WtF) + lane;
#pragma unroll
    for (int k0s = 0; k0s < 4; ++k0s) {
        int k0 = k0s * 32;
        half8 af;
        if constexpr (sizeof(InT) == 4) {
            const float* ap = (const float*)A + (size_t)arow * 128 + k0 + quad * 8;
            float4 v0 = *reinterpret_cast<const float4*>(ap);
            float4 v1 = *reinterpret_cast<const float4*>(ap + 4);
            af[0] = (_Float16)v0.x; af[1] = (_Float16)v0.y;
            af[2] = (_Float16)v0.z; af[3] = (_Float16)v0.w;
            af[4] = (_Float16)v1.x; af[5] = (_Float16)v1.y;
            af[6] = (_Float16)v1.z; af[7] = (_Float16)v1.w;
        } else {
            af = *reinterpret_cast<const half8*>((const __half*)A + (size_t)arow * 128 + k0 + quad * 8);
        }
#pragma unroll
        for (int t = 0; t < NT; ++t) {
            half8 bf = wf[(k0s * NT + t) * 64];
            acc[t] = __builtin_amdgcn_mfma_f32_16x16x32_f16(af, bf, acc[t], 0, 0, 0);
        }
    }
    // epilogue
    float sa[NT], da[NT];
#pragma unroll
    for (int t = 0; t < NT; ++t) {
        sa[t] = a_src[t * 16 + col];
        da[t] = a_dst[t * 16 + col];
    }
    int rbase = row0 + quad * 4;
#pragma unroll
    for (int reg = 0; reg < 4; ++reg) {
        int row = rbase + reg;
        bool live = row < M;
        if (live) {
#pragma unroll
            for (int t = 0; t < NT; ++t)
                C[(size_t)row * NC + t * 16 + col] = __float2half(acc[t][reg]);
        }
#pragma unroll
        for (int h = 0; h < H; ++h) {
            float ps = 0.f, pd = 0.f;
#pragma unroll
            for (int tt = 0; tt < TPH; ++tt) {
                int t = h * TPH + tt;
                ps = fmaf(acc[t][reg], sa[t], ps);
                pd = fmaf(acc[t][reg], da[t], pd);
            }
#pragma unroll
            for (int o = 1; o < 16; o <<= 1) {
                ps += __shfl_xor(ps, o, 64);
                pd += __shfl_xor(pd, o, 64);
            }
            if (col == 0 && live) {
                as[(size_t)row * H + h] = ps * LOG2E;
                ad[(size_t)row * H + h] = pd * LOG2E;
            }
        }
    }
}

// ---------------- aggregation: 4 dst nodes per wave, 16 lanes per node ----------------
// Global-interleaved descending-rank order via order[] -> wave gets 4 nodes of
// the same rank class (uniform md) in global-LPT arrangement.
// 4-edge unroll (load-grouped).

template <int CPL>
__device__ __forceinline__ void ldrow(const __half* __restrict__ p, _Float16* f) {
    if constexpr (CPL == 8) {
        half8 v = *reinterpret_cast<const half8*>(p);
#pragma unroll
        for (int c = 0; c < 8; ++c) f[c] = v[c];
    } else {
        half4 v = *reinterpret_cast<const half4*>(p);
#pragma unroll
        for (int c = 0; c < 4; ++c) f[c] = v[c];
    }
}

template <int H, int ROWS, int CW, bool DOELU, typename OutT>
__global__ __launch_bounds__(256) void aggregateQ(const __half* __restrict__ h,
                                                  const float* __restrict__ as,
                                                  const float* __restrict__ ad,
                                                  const int* __restrict__ offs,
                                                  const int* __restrict__ srcs,
                                                  const int* __restrict__ order,
                                                  const float* __restrict__ bias,
                                                  OutT* __restrict__ out, int N) {
    constexpr int CPL = CW / 16;    // channels per lane (8 or 4)
    unsigned wave = (blockIdx.x * blockDim.x + threadIdx.x) >> 6;
    unsigned lane = threadIdx.x & 63;
    unsigned lig = lane & 15;       // lane in group
    unsigned idx = wave * 4u + (lane >> 4);
    bool live = idx < (unsigned)N;
    unsigned nc = (unsigned)order[live ? idx : 0u];
    unsigned chan = lig * CPL;
    unsigned head = (chan * H) / ROWS;
    float adv = ad[nc * H + head];
    int e0 = offs[nc], e1 = offs[nc + 1];
    int deg = e1 - e0, e1m1 = e1 - 1;
    int md = deg;
    md = max(md, __shfl_xor(md, 16, 64));
    md = max(md, __shfl_xor(md, 32, 64));
    float accs[CPL] = {};
    float den = 0.f;
    for (int k = 0; k < md; k += 4) {
        int b = e0 + k;
        unsigned j0 = (unsigned)srcs[min(b, e1m1)];
        unsigned j1 = (unsigned)srcs[min(b + 1, e1m1)];
        unsigned j2 = (unsigned)srcs[min(b + 2, e1m1)];
        unsigned j3 = (unsigned)srcs[min(b + 3, e1m1)];
        float t0 = as[j0 * H + head] + adv;
        float t1 = as[j1 * H + head] + adv;
        float t2 = as[j2 * H + head] + adv;
        float t3 = as[j3 * H + head] + adv;
        _Float16 f0[CPL], f1[CPL], f2[CPL], f3[CPL];
        ldrow<CPL>(h + j0 * (unsigned)ROWS + chan, f0);
        ldrow<CPL>(h + j1 * (unsigned)ROWS + chan, f1);
        ldrow<CPL>(h + j2 * (unsigned)ROWS + chan, f2);
        ldrow<CPL>(h + j3 * (unsigned)ROWS + chan, f3);
        float x0 = exp2_fast(fmaxf(t0, 0.2f * t0));
        float x1 = exp2_fast(fmaxf(t1, 0.2f * t1));
        float x2 = exp2_fast(fmaxf(t2, 0.2f * t2));
        float x3 = exp2_fast(fmaxf(t3, 0.2f * t3));
        x0 = (k < deg) ? x0 : 0.f;
        x1 = (k + 1 < deg) ? x1 : 0.f;
        x2 = (k + 2 < deg) ? x2 : 0.f;
        x3 = (k + 3 < deg) ? x3 : 0.f;
#pragma unroll
        for (int c = 0; c < CPL; ++c) accs[c] = fmaf(x0, (float)f0[c], accs[c]);
#pragma unroll
        for (int c = 0; c < CPL; ++c) accs[c] = fmaf(x1, (float)f1[c], accs[c]);
#pragma unroll
        for (int c = 0; c < CPL; ++c) accs[c] = fmaf(x2, (float)f2[c], accs[c]);
#pragma unroll
        for (int c = 0; c < CPL; ++c) accs[c] = fmaf(x3, (float)f3[c], accs[c]);
        den += x0 + x1;
        den += x2 + x3;
    }
    float r = 1.0f / (den + 1e-16f);
    if (!live) return;
    const float* bp = bias + chan;
    float vs[CPL];
#pragma unroll
    for (int c = 0; c < CPL; ++c) {
        float v = accs[c] * r + bp[c];
        if constexpr (DOELU) v = (v > 0.f) ? v : expm1f(v);
        vs[c] = v;
    }
    if constexpr (sizeof(OutT) == 2) {
        __half2 st[CPL / 2];
#pragma unroll
        for (int q = 0; q < CPL / 2; ++q)
            st[q] = __floats2half2_rn(vs[2 * q], vs[2 * q + 1]);
        if constexpr (CPL == 8) {
            uint4 v; memcpy(&v, st, 16);
            *reinterpret_cast<uint4*>((__half*)out + nc * (unsigned)ROWS + chan) = v;
        } else {
            uint2 v; memcpy(&v, st, 8);
            *reinterpret_cast<uint2*>((__half*)out + nc * (unsigned)ROWS + chan) = v;
        }
    } else {
#pragma unroll
        for (int q4 = 0; q4 < CPL; q4 += 4) {
            float4 v = make_float4(vs[q4], vs[q4 + 1], vs[q4 + 2], vs[q4 + 3]);
            *reinterpret_cast<float4*>((float*)out + nc * (unsigned)ROWS + chan + q4) = v;
        }
    }
}

// ---------------- launch ----------------

extern "C" void kernel_launch(void* const* d_in, const int* in_sizes, int n_in,
                              void* d_out, int out_size, void* d_ws, size_t ws_size,
                              hipStream_t stream) {
    const float* x      = (const float*)d_in[0];
    const int*   ei     = (const int*)d_in[1];
    const float* W1     = (const float*)d_in[2];
    const float* a_src1 = (const float*)d_in[3];
    const float* a_dst1 = (const float*)d_in[4];
    const float* b1     = (const float*)d_in[5];
    const float* W2     = (const float*)d_in[6];
    const float* a_src2 = (const float*)d_in[7];
    const float* a_dst2 = (const float*)d_in[8];
    const float* b2     = (const float*)d_in[9];
    float* out = (float*)d_out;

    const int N = out_size / 64;          // 100000
    const int E = in_sizes[1] / 2;        // 1600000
    const int Etot = E + N;

    size_t off = 0;
    auto carve = [&](size_t bytes) -> void* {
        void* p = (char*)d_ws + off;
        off += (bytes + 255) & ~(size_t)255;
        return p;
    };
    __half* h1      = (__half*)carve((size_t)N * 128 * 2);   // fp16 h, layer 1
    __half* hmid    = (__half*)carve((size_t)N * 128 * 2);   // fp16 ELU output
    float* as1      = (float*)carve((size_t)N * 4 * 4);
    float* ad1      = (float*)carve((size_t)N * 4 * 4);
    float* as2      = (float*)carve((size_t)N * 4);
    float* ad2      = (float*)carve((size_t)N * 4);
    int*   offs     = (int*)carve((size_t)(N + 1) * 4);
    int*   srcs     = (int*)carve((size_t)Etot * 4);
    unsigned* rec   = (unsigned*)carve((size_t)Etot * 4);
    int*   order    = (int*)carve((size_t)N * 4);            // own buffer (no rec alias)
    unsigned* bcount  = (unsigned*)carve(NBK * 4);
    unsigned* bbase   = (unsigned*)carve((NBK + 1) * 4);
    unsigned* bcursor = (unsigned*)carve(NBK * 4);
    __half* WtF1    = (__half*)carve(128 * 128 * 2);
    __half* WtF2    = (__half*)carve(64 * 128 * 2);
    __half* h2      = h1;          // alias: h1 dead after aggregate1

    const int NSB = (N + DPB - 1) / DPB;   // sort blocks (196)
    const int GB  = (N + 63) / 64;         // gemm blocks (1563)

    // CSR build via bucketed counting sort (shared by both layers);
    // weight fragment prep rides along as extra blocks (independent work).
    hipMemsetAsync(bcount, 0, NBK * sizeof(unsigned), stream);
    bucket_hist<<<HB + 12, 256, 0, stream>>>(ei, E, N, bcount, W1, W2, WtF1, WtF2);
    scan_buckets<<<1, 256, 0, stream>>>(bcount, bbase, bcursor);
    bucket_scatter<<<(Etot + CH1 - 1) / CH1, 256, 0, stream>>>(ei, E, N, bcursor, rec);
    bucket_sort<<<NSB, 256, 0, stream>>>(rec, bbase, offs, srcs, order, N, Etot);

    // Layer 1: MFMA gemm (alphas fused) + single-pass aggregation
    gemm_mfma<128, 4, float><<<GB, 256, 0, stream>>>(
        x, WtF1, h1, a_src1, a_dst1, as1, ad1, N);
    aggregateQ<4, 128, 128, true, __half><<<(N + 15) / 16, 256, 0, stream>>>(
        h1, as1, ad1, offs, srcs, order, b1, hmid, N);

    // Layer 2
    gemm_mfma<64, 1, __half><<<GB, 256, 0, stream>>>(
        hmid, WtF2, h2, a_src2, a_dst2, as2, ad2, N);
    aggregateQ<1, 64, 64, false, float><<<(N + 15) / 16, 256, 0, stream>>>(
        h2, as2, ad2, offs, srcs, order, b2, out, N);
}